// Round 8
// baseline (274.339 us; speedup 1.0000x reference)
//
#include <hip/hip_runtime.h>
#include <math.h>

#define NUM_CLASSES 80
#define MT 50              // max targets per image
#define ATOT 8400          // 80*80 + 40*40 + 20*20
#define CH 85              // 5 + NUM_CLASSES
#define BLOCK 256
#define TILE 80            // anchors per block (8400 = 105 * 80)
#define NBLK 105           // blocks per image
#define EPB (TILE * CH)    // 6800 floats per block
#define GPB (EPB / 4)      // 1700 float4-groups per block
#define NITER 7            // ceil(GPB / BLOCK)

__device__ __forceinline__ float softplus_fast(float x) {
    // stable softplus via HW transcendentals: max(x,0) + log(1 + exp(-|x|))
    return fmaxf(x, 0.0f) + __logf(1.0f + __expf(-fabsf(x)));
}

// One block = (image b, 80-anchor tile). Single unconditional coalesced pass
// over the tile's 27.2KB pred slice; box channels parked in LDS for IoU.
__global__ __launch_bounds__(BLOCK) void yolox_fused(
        const float* __restrict__ pred,   // [B, ATOT, CH]
        const float* __restrict__ tgt,    // [B, MT, 5]
        const int*   __restrict__ isz,
        float* __restrict__ acc) {        // [B, NBLK, 4] obj, cls, box, np
    const int b   = blockIdx.y;
    const int blk = blockIdx.x;
    const int a0  = blk * TILE;
    const int tid = threadIdx.x;

    __shared__ float2 sxy[64];
    __shared__ float2 swh[64];
    __shared__ float  scls[64];
    __shared__ int    snv;
    __shared__ float  sposf[TILE];    // 1.0 if pos else 0.0
    __shared__ int    sgcls[TILE];    // matched class (or -1)
    __shared__ int    sbestm[TILE];   // matched target slot
    __shared__ float  sbox[TILE][4];  // pred[a][0..3] parked by the sweep

    // ---- wave-0 ballot compaction of valid targets (order-preserving) ----
    if (tid < 64) {
        const int m = tid;
        const float fsize = (float)(*isz);
        float c = -1.0f, x = 0.f, y = 0.f, w = 0.f, h = 0.f;
        if (m < MT) {
            const float* tb = tgt + (size_t)b * MT * 5 + (size_t)m * 5;
            c = tb[0];
            x = tb[1] * fsize; y = tb[2] * fsize;
            w = tb[3] * fsize; h = tb[4] * fsize;
        }
        const bool valid = (m < MT) && (c >= 0.0f);
        const unsigned long long ballot = __ballot(valid);
        const int slot = __popcll(ballot & ((1ull << tid) - 1ull));
        if (valid) {
            sxy[slot]  = make_float2(x, y);
            swh[slot]  = make_float2(w, h);
            scls[slot] = c;
        }
        if (m == 0) snv = (int)__popcll(ballot);
    }
    __syncthreads();
    const int nv = snv;

    // ---------------- Phase 1: match (threads 0..TILE-1) ----------------
    if (tid < TILE) {
        const int a = a0 + tid;
        float ax, ay;
        if (a < 6400)      { const int yy = a / 80;              const int xx = a - yy * 80;  ax = (float)(xx * 8  + 4);  ay = (float)(yy * 8  + 4); }
        else if (a < 8000) { const int i2 = a - 6400; const int yy = i2 / 40; const int xx = i2 - yy * 40; ax = (float)(xx * 16 + 8);  ay = (float)(yy * 16 + 8); }
        else               { const int i2 = a - 8000; const int yy = i2 / 20; const int xx = i2 - yy * 20; ax = (float)(xx * 32 + 16); ay = (float)(yy * 32 + 16); }

        float best = INFINITY;
        int bestm = 0;
        for (int m = 0; m < nv; ++m) {
            const float2 g = sxy[m];
            const float dx = g.x - ax, dy = g.y - ay;
            const float d2 = dx * dx + dy * dy;
            if (d2 < best) { best = d2; bestm = m; }
        }
        const bool pos = best < 4096.0f;  // 64^2
        sposf[tid]  = pos ? 1.0f : 0.0f;
        sgcls[tid]  = pos ? (int)scls[bestm] : -1;
        sbestm[tid] = bestm;
    }
    __syncthreads();

    // ---------------- Phase 2: unconditional coalesced sweep ----------------
    const float* base = pred + ((size_t)b * ATOT + (size_t)a0) * CH;

    float4 x[NITER];
    int    cc[NITER], la[NITER];
    bool   ok[NITER];
    #pragma unroll
    for (int k = 0; k < NITER; ++k) {
        const int g  = k * BLOCK + tid;
        ok[k] = (g < GPB);                    // constant-true for k < 6
        const int le = g << 2;
        const unsigned u = __umulhi((unsigned)le, 3233857729u) >> 6;  // le/85
        la[k] = (int)u;
        cc[k] = le - (int)u * CH;
        x[k] = ok[k] ? *(const float4*)(base + le)
                     : make_float4(0.f, 0.f, 0.f, 0.f);
    }

    float obj_s = 0.f, cls_s = 0.f;
    #pragma unroll
    for (int k = 0; k < NITER; ++k) {
        if (!ok[k]) continue;
        const float xs[4] = {x[k].x, x[k].y, x[k].z, x[k].w};
        #pragma unroll
        for (int j = 0; j < 4; ++j) {
            int c  = cc[k] + j;
            int lj = la[k];
            if (c >= CH) { c -= CH; ++lj; }   // group straddles anchor boundary
            const float xv = xs[j];
            const float pf = sposf[lj];
            const float sp = softplus_fast(xv);
            if (c < 4) {
                sbox[lj][c] = xv;             // park box channel for phase 3
            } else if (c == 4) {
                obj_s += sp - pf * xv;
            } else {
                cls_s += pf * (sp - ((c - 5 == sgcls[lj]) ? xv : 0.0f));
            }
        }
    }
    __syncthreads();

    // ---------------- Phase 3: IoU for pos anchors (threads 0..TILE-1) ------
    float box_s = 0.f, np_s = 0.f;
    if (tid < TILE && sposf[tid] > 0.0f) {
        np_s = 1.0f;
        const float pcx = sbox[tid][0], pcy = sbox[tid][1];
        const float pw = __expf(sbox[tid][2]), ph = __expf(sbox[tid][3]);
        const int bestm = sbestm[tid];
        const float2 g  = sxy[bestm];
        const float2 wh = swh[bestm];
        const float p1x = pcx - pw * 0.5f, p2x = pcx + pw * 0.5f;
        const float p1y = pcy - ph * 0.5f, p2y = pcy + ph * 0.5f;
        const float t1x = g.x - wh.x * 0.5f, t2x = g.x + wh.x * 0.5f;
        const float t1y = g.y - wh.y * 0.5f, t2y = g.y + wh.y * 0.5f;
        const float iw = fminf(p2x, t2x) - fmaxf(p1x, t1x);
        const float ih = fminf(p2y, t2y) - fmaxf(p1y, t1y);
        const float inter = fmaxf(iw, 0.f) * fmaxf(ih, 0.f);
        const float pa = (p2x - p1x) * (p2y - p1y);
        const float ta = (t2x - t1x) * (t2y - t1y);
        const float uni = pa + ta - inter;
        box_s = 1.0f - inter / (uni + 1e-6f);
    }

    // ---------------- Combined block reduction ----------------
    float v0 = obj_s, v1 = cls_s, v2 = box_s, v3 = np_s;
    for (int off = 32; off > 0; off >>= 1) {
        v0 += __shfl_down(v0, off, 64);
        v1 += __shfl_down(v1, off, 64);
        v2 += __shfl_down(v2, off, 64);
        v3 += __shfl_down(v3, off, 64);
    }
    __shared__ float sred[BLOCK / 64][4];
    const int wave = tid >> 6;
    const int lane = tid & 63;
    if (lane == 0) {
        sred[wave][0] = v0; sred[wave][1] = v1;
        sred[wave][2] = v2; sred[wave][3] = v3;
    }
    __syncthreads();
    if (tid == 0) {
        float t0 = 0.f, t1 = 0.f, t2 = 0.f, t3 = 0.f;
        #pragma unroll
        for (int w = 0; w < BLOCK / 64; ++w) {
            t0 += sred[w][0]; t1 += sred[w][1];
            t2 += sred[w][2]; t3 += sred[w][3];
        }
        float* slot = acc + ((size_t)b * NBLK + blk) * 4;
        slot[0] = t0; slot[1] = t1; slot[2] = t2; slot[3] = t3;
    }
}

// ---------------- Stage 2: per-image normalize + final reduce ---------------
__global__ __launch_bounds__(BLOCK) void yolox_stage2(
        const float* __restrict__ acc,    // [B, NBLK, 4]
        float* __restrict__ out, int B) {
    float obj = 0.f, cls = 0.f, box = 0.f, np = 0.f;
    for (int bb = threadIdx.x; bb < B; bb += BLOCK) {
        float os = 0.f, cs = 0.f, bs = 0.f, ps = 0.f;
        const float* s = acc + (size_t)bb * NBLK * 4;
        #pragma unroll 8
        for (int j = 0; j < NBLK; ++j) {
            os += s[j * 4 + 0];
            cs += s[j * 4 + 1];
            bs += s[j * 4 + 2];
            ps += s[j * 4 + 3];
        }
        obj += os * (1.0f / (float)ATOT);
        const float denom = fmaxf(ps, 1.0f);
        cls += (ps > 0.f) ? cs / (denom * (float)NUM_CLASSES) : 0.f;
        box += (ps > 0.f) ? bs / denom : 0.f;
        np  += ps;
    }
    float v0 = obj, v1 = cls, v2 = box, v3 = np;
    for (int off = 32; off > 0; off >>= 1) {
        v0 += __shfl_down(v0, off, 64);
        v1 += __shfl_down(v1, off, 64);
        v2 += __shfl_down(v2, off, 64);
        v3 += __shfl_down(v3, off, 64);
    }
    __shared__ float sred[BLOCK / 64][4];
    const int wave = threadIdx.x >> 6;
    const int lane = threadIdx.x & 63;
    if (lane == 0) {
        sred[wave][0] = v0; sred[wave][1] = v1;
        sred[wave][2] = v2; sred[wave][3] = v3;
    }
    __syncthreads();
    if (threadIdx.x == 0) {
        float t0 = 0.f, t1 = 0.f, t2 = 0.f, t3 = 0.f;
        #pragma unroll
        for (int w = 0; w < BLOCK / 64; ++w) {
            t0 += sred[w][0]; t1 += sred[w][1];
            t2 += sred[w][2]; t3 += sred[w][3];
        }
        out[0] = 5.0f * t2 + t0 + t1;  // total
        out[1] = t2;
        out[2] = t0;
        out[3] = t1;
        out[4] = t3;
    }
}

extern "C" void kernel_launch(void* const* d_in, const int* in_sizes, int n_in,
                              void* d_out, int out_size, void* d_ws, size_t ws_size,
                              hipStream_t stream) {
    const float* pred = (const float*)d_in[0];
    const float* tgt  = (const float*)d_in[1];
    const int*   isz  = (const int*)d_in[2];
    float* out = (float*)d_out;
    float* acc = (float*)d_ws;   // B*NBLK*4 floats

    const int B = in_sizes[1] / (MT * 5);

    dim3 grid(NBLK, B);
    yolox_fused<<<grid, BLOCK, 0, stream>>>(pred, tgt, isz, acc);
    yolox_stage2<<<1, BLOCK, 0, stream>>>(acc, out, B);
}